// Round 2
// baseline (513.990 us; speedup 1.0000x reference)
//
#include <hip/hip_runtime.h>

#define SEQ 4096
#define CDN 0.35355339059327379f   // 64^(-1/4)
#define DIAGC 0.0625f              // 0.5 * CDN^2
#define KEPS 1e-4f

typedef _Float16 f16;
typedef f16 f16x8 __attribute__((ext_vector_type(8)));
typedef f16 f16x4 __attribute__((ext_vector_type(4)));
typedef float f32x4 __attribute__((ext_vector_type(4)));

#define MFMA16(a, b, c) __builtin_amdgcn_mfma_f32_16x16x32_f16(a, b, c, 0, 0, 0)

// proj LDS: 256 rows x stride 72 f16 (144 B rows: 16B-aligned b128 reads, <=2-way banks)
#define PSTR 72

__device__ __forceinline__ void stage_proj(const float* __restrict__ proj, f16* plds) {
  int t = threadIdx.x;
  int mrow = t >> 2;
  int cb = (t & 3) * 16;
#pragma unroll
  for (int p = 0; p < 4; ++p) {
    int m = mrow + p * 64;
    const float4* src = (const float4*)(proj + m * 64 + cb);
    f16* dst = plds + m * PSTR + cb;
#pragma unroll
    for (int i = 0; i < 4; ++i) {
      float4 v = src[i];
      f16x4 h = {(f16)v.x, (f16)v.y, (f16)v.z, (f16)v.w};
      *(f16x4*)(dst + i * 4) = h;
    }
  }
}

// fragment of proj rows [16*mtile + (lane&15)], d = ks*32 + (lane>>4)*8 .. +7
__device__ __forceinline__ f16x8 proj_frag(const f16* plds, int mtile, int ks, int lane) {
  int m = (lane & 15) + 16 * mtile;
  return *(const f16x8*)(plds + m * PSTR + ks * 32 + (lane >> 4) * 8);
}

// row fragment of q/k: row = base_row + (lane&15), d = ks*32 + (lane>>4)*8 .. +7, scaled by CDN
// accumulates sum of squares (unscaled) into sq
__device__ __forceinline__ f16x8 row_frag(const float* __restrict__ base, int lane, int ks, float& sq) {
  const float4* p = (const float4*)(base + (size_t)(lane & 15) * 64 + ks * 32 + (lane >> 4) * 8);
  float4 a = p[0], b = p[1];
  sq += a.x*a.x + a.y*a.y + a.z*a.z + a.w*a.w + b.x*b.x + b.y*b.y + b.z*b.z + b.w*b.w;
  f16x8 r = {(f16)(a.x*CDN), (f16)(a.y*CDN), (f16)(a.z*CDN), (f16)(a.w*CDN),
             (f16)(b.x*CDN), (f16)(b.y*CDN), (f16)(b.z*CDN), (f16)(b.w*CDN)};
  return r;
}

// ---------------- K1: per-bh global max of dd_k -> 16 partials per bh ----------------
__global__ __launch_bounds__(256, 2) void k1_stab(
    const float* __restrict__ kk, const float* __restrict__ proj,
    float* __restrict__ ws_stab) {
  __shared__ f16 plds[256 * PSTR];
  __shared__ float wred[4];
  int bh = blockIdx.x >> 4, blk = blockIdx.x & 15;
  stage_proj(proj, plds);
  __syncthreads();
  int w = threadIdx.x >> 6, lane = threadIdx.x & 63;
  const float* kbh = kk + (size_t)bh * SEQ * 64;
  float rmax = -1e30f;
#pragma unroll 1
  for (int it = 0; it < 4; ++it) {
    int n0 = blk * 256 + w * 64 + it * 16;
    float sq = 0.f;
    f16x8 b0 = row_frag(kbh + (size_t)n0 * 64, lane, 0, sq);
    f16x8 b1 = row_frag(kbh + (size_t)n0 * 64, lane, 1, sq);
#pragma unroll
    for (int mt = 0; mt < 16; ++mt) {
      f32x4 acc = {0.f, 0.f, 0.f, 0.f};
      acc = MFMA16(proj_frag(plds, mt, 0, lane), b0, acc);
      acc = MFMA16(proj_frag(plds, mt, 1, lane), b1, acc);
      rmax = fmaxf(rmax, fmaxf(fmaxf(acc[0], acc[1]), fmaxf(acc[2], acc[3])));
    }
  }
#pragma unroll
  for (int m = 1; m < 64; m <<= 1) rmax = fmaxf(rmax, __shfl_xor(rmax, m, 64));
  if (lane == 0) wred[w] = rmax;
  __syncthreads();
  if (threadIdx.x == 0)
    ws_stab[bh * 16 + blk] = fmaxf(fmaxf(wred[0], wred[1]), fmaxf(wred[2], wred[3]));
}

// ---------------- K2: context[m][e] and k_cumsum[m] via atomic fp32 accumulation -----
// ws_ctx lives in d_out scratch (consumed by K2b before K3 overwrites d_out).
__global__ __launch_bounds__(256, 2) void k2_ctx(
    const float* __restrict__ kk, const float* __restrict__ vv,
    const float* __restrict__ proj, const float* __restrict__ ws_stab,
    float* __restrict__ ws_kcum, float* __restrict__ ws_ctx) {
  __shared__ f16 plds[256 * PSTR];
  __shared__ __align__(16) f16 vt[64 * 40];       // v^T [e][n32], stride 40 f16 = 80 B
  __shared__ __align__(16) f16 pht[4][64 * 40];   // per-wave phi^T [m_local 64][n32]
  __shared__ __align__(16) float diag_s[4][32];
  int bh = blockIdx.x >> 3, s = blockIdx.x & 7;
  stage_proj(proj, plds);
  float stab = -1e30f;
#pragma unroll
  for (int i = 0; i < 16; ++i) stab = fmaxf(stab, ws_stab[bh * 16 + i]);
  int w = threadIdx.x >> 6, lane = threadIdx.x & 63;
  int q4 = lane >> 4, l15 = lane & 15;
  const float* kbh = kk + (size_t)bh * SEQ * 64;
  const float* vbh = vv + (size_t)bh * SEQ * 64;
  f32x4 actx[4][4];
  f32x4 akc[4];
#pragma unroll
  for (int i = 0; i < 4; ++i) {
    akc[i] = (f32x4){0.f, 0.f, 0.f, 0.f};
#pragma unroll
    for (int j = 0; j < 4; ++j) actx[i][j] = (f32x4){0.f, 0.f, 0.f, 0.f};
  }
  f16x8 ones = {(f16)1.f, (f16)1.f, (f16)1.f, (f16)1.f,
                (f16)1.f, (f16)1.f, (f16)1.f, (f16)1.f};
  __syncthreads();
#pragma unroll 1
  for (int it = 0; it < 16; ++it) {
    int n0 = s * 512 + it * 32;
    // cooperative v -> vt (transposed, f16)
    {
      int vr = threadIdx.x >> 3, ec = (threadIdx.x & 7) * 8;
      const float4* vp = (const float4*)(vbh + (size_t)(n0 + vr) * 64 + ec);
      float4 a = vp[0], b = vp[1];
      vt[(ec + 0) * 40 + vr] = (f16)a.x;
      vt[(ec + 1) * 40 + vr] = (f16)a.y;
      vt[(ec + 2) * 40 + vr] = (f16)a.z;
      vt[(ec + 3) * 40 + vr] = (f16)a.w;
      vt[(ec + 4) * 40 + vr] = (f16)b.x;
      vt[(ec + 5) * 40 + vr] = (f16)b.y;
      vt[(ec + 6) * 40 + vr] = (f16)b.z;
      vt[(ec + 7) * 40 + vr] = (f16)b.w;
    }
    // k row frags (A-operand) + per-row diag
    f16x8 ak[2][2];
    float dg[2];
#pragma unroll
    for (int nt = 0; nt < 2; ++nt) {
      float sq = 0.f;
      ak[nt][0] = row_frag(kbh + (size_t)(n0 + nt * 16) * 64, lane, 0, sq);
      ak[nt][1] = row_frag(kbh + (size_t)(n0 + nt * 16) * 64, lane, 1, sq);
      sq += __shfl_xor(sq, 16, 64);
      sq += __shfl_xor(sq, 32, 64);
      dg[nt] = sq * DIAGC;  // diag for row l15 of tile nt (all lanes have it)
    }
    if (lane < 16) {
      diag_s[w][lane] = dg[0];
      diag_s[w][16 + lane] = dg[1];
    }
    // dd (C layout: row n = q4*4+reg, col m = l15) -> phi -> pht[w] (per-wave, lockstep)
#pragma unroll
    for (int mtl = 0; mtl < 4; ++mtl) {
      f16x8 bp0 = proj_frag(plds, w * 4 + mtl, 0, lane);
      f16x8 bp1 = proj_frag(plds, w * 4 + mtl, 1, lane);
#pragma unroll
      for (int nt = 0; nt < 2; ++nt) {
        f32x4 acc = {0.f, 0.f, 0.f, 0.f};
        acc = MFMA16(ak[nt][0], bp0, acc);
        acc = MFMA16(ak[nt][1], bp1, acc);
        float4 dgv = ((const float4*)&diag_s[w][0])[nt * 4 + q4];
        f16x4 ph;
        ph[0] = (f16)(__expf(acc[0] - dgv.x - stab) + KEPS);
        ph[1] = (f16)(__expf(acc[1] - dgv.y - stab) + KEPS);
        ph[2] = (f16)(__expf(acc[2] - dgv.z - stab) + KEPS);
        ph[3] = (f16)(__expf(acc[3] - dgv.w - stab) + KEPS);
        *(f16x4*)(&pht[w][(16 * mtl + l15) * 40 + nt * 16 + q4 * 4]) = ph;
      }
    }
    __syncthreads();  // vt ready
    f16x8 bv[4];
#pragma unroll
    for (int et = 0; et < 4; ++et)
      bv[et] = *(const f16x8*)(vt + (l15 + 16 * et) * 40 + q4 * 8);
#pragma unroll
    for (int mtl = 0; mtl < 4; ++mtl) {
      f16x8 aph = *(const f16x8*)(&pht[w][(16 * mtl + l15) * 40 + q4 * 8]);
      akc[mtl] = MFMA16(aph, ones, akc[mtl]);  // k_cumsum via ones-vector
#pragma unroll
      for (int et = 0; et < 4; ++et)
        actx[mtl][et] = MFMA16(aph, bv[et], actx[mtl][et]);
    }
    __syncthreads();  // protect vt before next overwrite
  }
  float* ctxbh = ws_ctx + (size_t)bh * 256 * 64;
#pragma unroll 1
  for (int mtl = 0; mtl < 4; ++mtl) {
    int mbase = (w * 4 + mtl) * 16 + q4 * 4;
#pragma unroll
    for (int et = 0; et < 4; ++et) {
      int e = l15 + 16 * et;
#pragma unroll
      for (int r = 0; r < 4; ++r)
        atomicAdd(&ctxbh[(size_t)(mbase + r) * 64 + e], actx[mtl][et][r]);
    }
    if (l15 == 0) {
#pragma unroll
      for (int r = 0; r < 4; ++r)
        atomicAdd(&ws_kcum[bh * 256 + mbase + r], akc[mtl][r]);
    }
  }
}

// ---------------- K2b: context fp32 [m][e] -> f16 ctxT [e][m] ----------------
__global__ __launch_bounds__(256) void k2b_t(
    const float* __restrict__ ws_ctx, f16* __restrict__ ws_ctxT) {
  int bh = blockIdx.x;
  const float* c = ws_ctx + (size_t)bh * 16384;
  f16* ct = ws_ctxT + (size_t)bh * 16384;
  for (int idx = threadIdx.x; idx < 16384; idx += 256) {
    int m = idx >> 6, e = idx & 63;
    ct[e * 256 + m] = (f16)c[idx];
  }
}

// ---------------- K3: dd_q -> phi_q -> out = (phi_q @ ctx) / (phi_q . kcum) ----------
__global__ __launch_bounds__(256, 2) void k3_out(
    const float* __restrict__ qq, const float* __restrict__ proj,
    const float* __restrict__ ws_kcum, const f16* __restrict__ ws_ctxT,
    float* __restrict__ out) {
  __shared__ f16 plds[256 * PSTR];
  __shared__ __align__(16) f16 pht[4][16 * 264];  // per-wave phi^T2 [n16][m256], stride 264 f16
  __shared__ __align__(16) float kcl[256];
  int bh = blockIdx.x >> 4, blk = blockIdx.x & 15;
  stage_proj(proj, plds);
  kcl[threadIdx.x] = ws_kcum[bh * 256 + threadIdx.x];
  __syncthreads();
  int w = threadIdx.x >> 6, lane = threadIdx.x & 63;
  int q4 = lane >> 4, l15 = lane & 15;
  const float* qbh = qq + (size_t)bh * SEQ * 64;
  const f16* ctb = ws_ctxT + (size_t)bh * 16384;
  float* obh = out + (size_t)bh * SEQ * 64;
#pragma unroll 1
  for (int it = 0; it < 4; ++it) {
    int n0 = blk * 256 + w * 64 + it * 16;
    float sq = 0.f;
    f16x8 bq0 = row_frag(qbh + (size_t)n0 * 64, lane, 0, sq);
    f16x8 bq1 = row_frag(qbh + (size_t)n0 * 64, lane, 1, sq);
    sq += __shfl_xor(sq, 16, 64);
    sq += __shfl_xor(sq, 32, 64);
    float diag = sq * DIAGC;  // diag for column n = n0 + l15 (ddT orientation)
    f32x4 dd[16];
#pragma unroll
    for (int mt = 0; mt < 16; ++mt) {
      f32x4 acc = {0.f, 0.f, 0.f, 0.f};
      acc = MFMA16(proj_frag(plds, mt, 0, lane), bq0, acc);
      acc = MFMA16(proj_frag(plds, mt, 1, lane), bq1, acc);
      dd[mt] = acc;  // ddT: row m = 16*mt + 4*q4 + reg, col n = l15
    }
    float st = -1e30f;
#pragma unroll
    for (int mt = 0; mt < 16; ++mt)
      st = fmaxf(st, fmaxf(fmaxf(dd[mt][0], dd[mt][1]), fmaxf(dd[mt][2], dd[mt][3])));
    st = fmaxf(st, __shfl_xor(st, 16, 64));
    st = fmaxf(st, __shfl_xor(st, 32, 64));  // per-row (per-column-here) max
    float dacc = 0.f;
#pragma unroll
    for (int mt = 0; mt < 16; ++mt) {
      float4 kc = ((const float4*)kcl)[mt * 4 + q4];
      float e0 = __expf(dd[mt][0] - diag - st) + KEPS;
      float e1 = __expf(dd[mt][1] - diag - st) + KEPS;
      float e2 = __expf(dd[mt][2] - diag - st) + KEPS;
      float e3 = __expf(dd[mt][3] - diag - st) + KEPS;
      dacc += e0 * kc.x + e1 * kc.y + e2 * kc.z + e3 * kc.w;
      f16x4 ph;
      ph[0] = (f16)e0; ph[1] = (f16)e1; ph[2] = (f16)e2; ph[3] = (f16)e3;
      *(f16x4*)(&pht[w][l15 * 264 + mt * 16 + q4 * 4]) = ph;
    }
    dacc += __shfl_xor(dacc, 16, 64);
    dacc += __shfl_xor(dacc, 32, 64);
    float dinv = 1.0f / dacc;
    f32x4 ao[4];
#pragma unroll
    for (int r = 0; r < 4; ++r) ao[r] = (f32x4){0.f, 0.f, 0.f, 0.f};
#pragma unroll
    for (int ks2 = 0; ks2 < 8; ++ks2) {
      f16x8 bph = *(const f16x8*)(&pht[w][l15 * 264 + ks2 * 32 + q4 * 8]);
#pragma unroll
      for (int rte = 0; rte < 4; ++rte) {
        f16x8 act = *(const f16x8*)(ctb + (size_t)(l15 + 16 * rte) * 256 + ks2 * 32 + q4 * 8);
        ao[rte] = MFMA16(act, bph, ao[rte]);  // outT: row e, col n
      }
    }
#pragma unroll
    for (int rte = 0; rte < 4; ++rte) {
      float4 o;
      o.x = ao[rte][0] * dinv;
      o.y = ao[rte][1] * dinv;
      o.z = ao[rte][2] * dinv;
      o.w = ao[rte][3] * dinv;
      *(float4*)(obh + (size_t)(n0 + l15) * 64 + rte * 16 + q4 * 4) = o;
    }
  }
}

extern "C" void kernel_launch(void* const* d_in, const int* in_sizes, int n_in,
                              void* d_out, int out_size, void* d_ws, size_t ws_size,
                              hipStream_t stream) {
  const float* q = (const float*)d_in[0];
  const float* k = (const float*)d_in[1];
  const float* v = (const float*)d_in[2];
  const float* proj = (const float*)d_in[3];
  float* out = (float*)d_out;
  float* ws = (float*)d_ws;
  // ws layout (floats): stab[64][16] | kcum[64][256] | ctxT f16[64][64][256]
  // total = 1024*4 + 16384*4 + 1048576*2 = 2,166,784 B  (~2.07 MB; previous 6.36 MB
  // version overflowed d_ws -> corrupted neighboring allocs -> launches 2..N wrong)
  float* ws_stab = ws;                    // 1024 floats
  float* ws_kcum = ws + 1024;             // 16384 floats
  f16*   ws_ctxT = (f16*)(ws + 17408);    // 1,048,576 f16
  // fp32 ctx accumulator (4 MB) lives in d_out scratch: K2 atomically accumulates,
  // K2b consumes it, then K3 overwrites every element of d_out with final output.
  float* ws_ctx = out;                    // 1,048,576 floats at head of d_out (64 MB)
  hipMemsetAsync(ws_kcum, 0, (size_t)16384 * sizeof(float), stream);
  hipMemsetAsync(ws_ctx, 0, (size_t)1048576 * sizeof(float), stream);
  k1_stab<<<1024, 256, 0, stream>>>(k, proj, ws_stab);
  k2_ctx<<<512, 256, 0, stream>>>(k, v, proj, ws_stab, ws_kcum, ws_ctx);
  k2b_t<<<64, 256, 0, stream>>>(ws_ctx, ws_ctxT);
  k3_out<<<1024, 256, 0, stream>>>(q, proj, ws_kcum, ws_ctxT, out);
}

// Round 3
// 486.672 us; speedup vs baseline: 1.0561x; 1.0561x over previous
//
#include <hip/hip_runtime.h>

#define SEQ 4096
#define CDN 0.35355339059327379f   // 64^(-1/4)
#define DIAGC 0.0625f              // 0.5 * CDN^2
#define KEPS 1e-4f

typedef _Float16 f16;
typedef f16 f16x8 __attribute__((ext_vector_type(8)));
typedef f16 f16x4 __attribute__((ext_vector_type(4)));
typedef float f32x4 __attribute__((ext_vector_type(4)));

#define MFMA16(a, b, c) __builtin_amdgcn_mfma_f32_16x16x32_f16(a, b, c, 0, 0, 0)

// proj LDS: 256 rows x stride 72 f16 (144 B rows: 16B-aligned b128 reads, <=2-way banks)
#define PSTR 72

__device__ __forceinline__ void stage_proj(const float* __restrict__ proj, f16* plds) {
  int t = threadIdx.x;
  int mrow = t >> 2;
  int cb = (t & 3) * 16;
#pragma unroll
  for (int p = 0; p < 4; ++p) {
    int m = mrow + p * 64;
    const float4* src = (const float4*)(proj + m * 64 + cb);
    f16* dst = plds + m * PSTR + cb;
#pragma unroll
    for (int i = 0; i < 4; ++i) {
      float4 v = src[i];
      f16x4 h = {(f16)v.x, (f16)v.y, (f16)v.z, (f16)v.w};
      *(f16x4*)(dst + i * 4) = h;
    }
  }
}

// fragment of proj rows [16*mtile + (lane&15)], d = ks*32 + (lane>>4)*8 .. +7
__device__ __forceinline__ f16x8 proj_frag(const f16* plds, int mtile, int ks, int lane) {
  int m = (lane & 15) + 16 * mtile;
  return *(const f16x8*)(plds + m * PSTR + ks * 32 + (lane >> 4) * 8);
}

// row fragment of q/k: row = base_row + (lane&15), d = ks*32 + (lane>>4)*8 .. +7, scaled by CDN
// accumulates sum of squares (unscaled) into sq
__device__ __forceinline__ f16x8 row_frag(const float* __restrict__ base, int lane, int ks, float& sq) {
  const float4* p = (const float4*)(base + (size_t)(lane & 15) * 64 + ks * 32 + (lane >> 4) * 8);
  float4 a = p[0], b = p[1];
  sq += a.x*a.x + a.y*a.y + a.z*a.z + a.w*a.w + b.x*b.x + b.y*b.y + b.z*b.z + b.w*b.w;
  f16x8 r = {(f16)(a.x*CDN), (f16)(a.y*CDN), (f16)(a.z*CDN), (f16)(a.w*CDN),
             (f16)(b.x*CDN), (f16)(b.y*CDN), (f16)(b.z*CDN), (f16)(b.w*CDN)};
  return r;
}

// ---------------- K1: per-bh global max of dd_k -> 8 partials per bh ----------------
__global__ __launch_bounds__(256, 2) void k1_stab(
    const float* __restrict__ kk, const float* __restrict__ proj,
    float* __restrict__ ws_stab) {
  __shared__ f16 plds[256 * PSTR];
  __shared__ float wred[4];
  int bh = blockIdx.x >> 3, blk = blockIdx.x & 7;
  stage_proj(proj, plds);
  __syncthreads();
  int w = threadIdx.x >> 6, lane = threadIdx.x & 63;
  const float* kbh = kk + (size_t)bh * SEQ * 64;
  float rmax = -1e30f;
#pragma unroll 1
  for (int it = 0; it < 8; ++it) {
    int n0 = blk * 512 + it * 64 + w * 16;
    float sq = 0.f;
    f16x8 b0 = row_frag(kbh + (size_t)n0 * 64, lane, 0, sq);
    f16x8 b1 = row_frag(kbh + (size_t)n0 * 64, lane, 1, sq);
#pragma unroll
    for (int mt = 0; mt < 16; ++mt) {
      f32x4 acc = {0.f, 0.f, 0.f, 0.f};
      acc = MFMA16(proj_frag(plds, mt, 0, lane), b0, acc);
      acc = MFMA16(proj_frag(plds, mt, 1, lane), b1, acc);
      rmax = fmaxf(rmax, fmaxf(fmaxf(acc[0], acc[1]), fmaxf(acc[2], acc[3])));
    }
  }
#pragma unroll
  for (int m = 1; m < 64; m <<= 1) rmax = fmaxf(rmax, __shfl_xor(rmax, m, 64));
  if (lane == 0) wred[w] = rmax;
  __syncthreads();
  if (threadIdx.x == 0)
    ws_stab[bh * 8 + blk] = fmaxf(fmaxf(wred[0], wred[1]), fmaxf(wred[2], wred[3]));
}

// ---------------- K2: per-block PARTIAL context[m][e] + k_cumsum[m], plain stores ----
// ctx_part[bh][s][256][64] and kcum_part[bh][s][256] live in d_out scratch
// (K2b consumes both strictly before K3 overwrites d_out).
__global__ __launch_bounds__(256, 2) void k2_ctx(
    const float* __restrict__ kk, const float* __restrict__ vv,
    const float* __restrict__ proj, const float* __restrict__ ws_stab,
    float* __restrict__ ctx_part, float* __restrict__ kcum_part) {
  __shared__ f16 plds[256 * PSTR];
  __shared__ __align__(16) f16 vt[64 * 40];       // v^T [e][n32], stride 40 f16 = 80 B
  __shared__ __align__(16) f16 pht[4][64 * 40];   // per-wave phi^T [m_local 64][n32]
  __shared__ __align__(16) float diag_s[4][32];
  int bh = blockIdx.x >> 3, s = blockIdx.x & 7;
  stage_proj(proj, plds);
  float stab = -1e30f;
#pragma unroll
  for (int i = 0; i < 8; ++i) stab = fmaxf(stab, ws_stab[bh * 8 + i]);
  int w = threadIdx.x >> 6, lane = threadIdx.x & 63;
  int q4 = lane >> 4, l15 = lane & 15;
  const float* kbh = kk + (size_t)bh * SEQ * 64;
  const float* vbh = vv + (size_t)bh * SEQ * 64;
  f32x4 actx[4][4];
  f32x4 akc[4];
#pragma unroll
  for (int i = 0; i < 4; ++i) {
    akc[i] = (f32x4){0.f, 0.f, 0.f, 0.f};
#pragma unroll
    for (int j = 0; j < 4; ++j) actx[i][j] = (f32x4){0.f, 0.f, 0.f, 0.f};
  }
  f16x8 ones = {(f16)1.f, (f16)1.f, (f16)1.f, (f16)1.f,
                (f16)1.f, (f16)1.f, (f16)1.f, (f16)1.f};
  __syncthreads();
#pragma unroll 1
  for (int it = 0; it < 16; ++it) {
    int n0 = s * 512 + it * 32;
    // cooperative v -> vt (transposed, f16)
    {
      int vr = threadIdx.x >> 3, ec = (threadIdx.x & 7) * 8;
      const float4* vp = (const float4*)(vbh + (size_t)(n0 + vr) * 64 + ec);
      float4 a = vp[0], b = vp[1];
      vt[(ec + 0) * 40 + vr] = (f16)a.x;
      vt[(ec + 1) * 40 + vr] = (f16)a.y;
      vt[(ec + 2) * 40 + vr] = (f16)a.z;
      vt[(ec + 3) * 40 + vr] = (f16)a.w;
      vt[(ec + 4) * 40 + vr] = (f16)b.x;
      vt[(ec + 5) * 40 + vr] = (f16)b.y;
      vt[(ec + 6) * 40 + vr] = (f16)b.z;
      vt[(ec + 7) * 40 + vr] = (f16)b.w;
    }
    // k row frags (A-operand) + per-row diag
    f16x8 ak[2][2];
    float dg[2];
#pragma unroll
    for (int nt = 0; nt < 2; ++nt) {
      float sq = 0.f;
      ak[nt][0] = row_frag(kbh + (size_t)(n0 + nt * 16) * 64, lane, 0, sq);
      ak[nt][1] = row_frag(kbh + (size_t)(n0 + nt * 16) * 64, lane, 1, sq);
      sq += __shfl_xor(sq, 16, 64);
      sq += __shfl_xor(sq, 32, 64);
      dg[nt] = sq * DIAGC;  // diag for row l15 of tile nt (all lanes have it)
    }
    if (lane < 16) {
      diag_s[w][lane] = dg[0];
      diag_s[w][16 + lane] = dg[1];
    }
    // dd (C layout: row n = q4*4+reg, col m = l15) -> phi -> pht[w] (per-wave, lockstep)
#pragma unroll
    for (int mtl = 0; mtl < 4; ++mtl) {
      f16x8 bp0 = proj_frag(plds, w * 4 + mtl, 0, lane);
      f16x8 bp1 = proj_frag(plds, w * 4 + mtl, 1, lane);
#pragma unroll
      for (int nt = 0; nt < 2; ++nt) {
        f32x4 acc = {0.f, 0.f, 0.f, 0.f};
        acc = MFMA16(ak[nt][0], bp0, acc);
        acc = MFMA16(ak[nt][1], bp1, acc);
        float4 dgv = ((const float4*)&diag_s[w][0])[nt * 4 + q4];
        f16x4 ph;
        ph[0] = (f16)(__expf(acc[0] - dgv.x - stab) + KEPS);
        ph[1] = (f16)(__expf(acc[1] - dgv.y - stab) + KEPS);
        ph[2] = (f16)(__expf(acc[2] - dgv.z - stab) + KEPS);
        ph[3] = (f16)(__expf(acc[3] - dgv.w - stab) + KEPS);
        *(f16x4*)(&pht[w][(16 * mtl + l15) * 40 + nt * 16 + q4 * 4]) = ph;
      }
    }
    __syncthreads();  // vt ready
    f16x8 bv[4];
#pragma unroll
    for (int et = 0; et < 4; ++et)
      bv[et] = *(const f16x8*)(vt + (l15 + 16 * et) * 40 + q4 * 8);
#pragma unroll
    for (int mtl = 0; mtl < 4; ++mtl) {
      f16x8 aph = *(const f16x8*)(&pht[w][(16 * mtl + l15) * 40 + q4 * 8]);
      akc[mtl] = MFMA16(aph, ones, akc[mtl]);  // k_cumsum via ones-vector
#pragma unroll
      for (int et = 0; et < 4; ++et)
        actx[mtl][et] = MFMA16(aph, bv[et], actx[mtl][et]);
    }
    __syncthreads();  // protect vt before next overwrite
  }
  // plain coalesced partial stores (16 lanes x 4B = 64B segments per instr)
  float* cpart = ctx_part + ((size_t)bh * 8 + s) * 16384;
  float* kcp = kcum_part + ((size_t)bh * 8 + s) * 256;
#pragma unroll 1
  for (int mtl = 0; mtl < 4; ++mtl) {
    int mbase = (w * 4 + mtl) * 16 + q4 * 4;
#pragma unroll
    for (int r = 0; r < 4; ++r) {
#pragma unroll
      for (int et = 0; et < 4; ++et)
        cpart[(size_t)(mbase + r) * 64 + l15 + 16 * et] = actx[mtl][et][r];
    }
    if (l15 == 0) {
#pragma unroll
      for (int r = 0; r < 4; ++r)
        kcp[mbase + r] = akc[mtl][r];
    }
  }
}

// ---------------- K2b: reduce 8 partials -> fp32 kcum + f16 ctxT [e][m] -------------
// 4 blocks per bh, each handles a 64-row m-range; LDS transpose for coalesced writes.
__global__ __launch_bounds__(256) void k2b_t(
    const float* __restrict__ ctx_part, const float* __restrict__ kcum_part,
    float* __restrict__ ws_kcum, f16* __restrict__ ws_ctxT) {
  __shared__ float tile[64 * 65];  // [m_local][e], stride 65 (conflict-free transpose)
  int bh = blockIdx.x >> 2, qm = blockIdx.x & 3;
  int m0 = qm * 64;
  const float* cp = ctx_part + (size_t)bh * 8 * 16384 + (size_t)m0 * 64;
  int t = threadIdx.x;
#pragma unroll
  for (int i = 0; i < 16; ++i) {
    int idx = t + i * 256;           // idx over [64m x 64e]
    int ml = idx >> 6, e = idx & 63;
    float acc = 0.f;
#pragma unroll
    for (int s = 0; s < 8; ++s) acc += cp[(size_t)s * 16384 + idx];
    tile[ml * 65 + e] = acc;
  }
  if (t < 64) {
    const float* kp = kcum_part + (size_t)bh * 8 * 256 + m0 + t;
    float acc = 0.f;
#pragma unroll
    for (int s = 0; s < 8; ++s) acc += kp[s * 256];
    ws_kcum[bh * 256 + m0 + t] = acc;
  }
  __syncthreads();
  f16* ct = ws_ctxT + (size_t)bh * 16384 + m0;
  int mj = t & 63, eg = t >> 6;
#pragma unroll
  for (int i = 0; i < 16; ++i) {
    int e = eg + i * 4;
    ct[(size_t)e * 256 + mj] = (f16)tile[mj * 65 + e];
  }
}

// ---------------- K3: dd_q -> phi_q -> out = (phi_q @ ctx) / (phi_q . kcum) ----------
__global__ __launch_bounds__(256, 2) void k3_out(
    const float* __restrict__ qq, const float* __restrict__ proj,
    const float* __restrict__ ws_kcum, const f16* __restrict__ ws_ctxT,
    float* __restrict__ out) {
  __shared__ f16 plds[256 * PSTR];
  __shared__ __align__(16) f16 pht[4][16 * 264];  // per-wave phi^T2 [n16][m256], stride 264 f16
  __shared__ __align__(16) float kcl[256];
  int bh = blockIdx.x >> 4, blk = blockIdx.x & 15;
  stage_proj(proj, plds);
  kcl[threadIdx.x] = ws_kcum[bh * 256 + threadIdx.x];
  __syncthreads();
  int w = threadIdx.x >> 6, lane = threadIdx.x & 63;
  int q4 = lane >> 4, l15 = lane & 15;
  const float* qbh = qq + (size_t)bh * SEQ * 64;
  const f16* ctb = ws_ctxT + (size_t)bh * 16384;
  float* obh = out + (size_t)bh * SEQ * 64;
#pragma unroll 1
  for (int it = 0; it < 4; ++it) {
    int n0 = blk * 256 + w * 64 + it * 16;
    float sq = 0.f;
    f16x8 bq0 = row_frag(qbh + (size_t)n0 * 64, lane, 0, sq);
    f16x8 bq1 = row_frag(qbh + (size_t)n0 * 64, lane, 1, sq);
    sq += __shfl_xor(sq, 16, 64);
    sq += __shfl_xor(sq, 32, 64);
    float diag = sq * DIAGC;  // diag for column n = n0 + l15 (ddT orientation)
    f32x4 dd[16];
#pragma unroll
    for (int mt = 0; mt < 16; ++mt) {
      f32x4 acc = {0.f, 0.f, 0.f, 0.f};
      acc = MFMA16(proj_frag(plds, mt, 0, lane), bq0, acc);
      acc = MFMA16(proj_frag(plds, mt, 1, lane), bq1, acc);
      dd[mt] = acc;  // ddT: row m = 16*mt + 4*q4 + reg, col n = l15
    }
    float st = -1e30f;
#pragma unroll
    for (int mt = 0; mt < 16; ++mt)
      st = fmaxf(st, fmaxf(fmaxf(dd[mt][0], dd[mt][1]), fmaxf(dd[mt][2], dd[mt][3])));
    st = fmaxf(st, __shfl_xor(st, 16, 64));
    st = fmaxf(st, __shfl_xor(st, 32, 64));  // per-row (per-column-here) max
    float dacc = 0.f;
#pragma unroll
    for (int mt = 0; mt < 16; ++mt) {
      float4 kc = ((const float4*)kcl)[mt * 4 + q4];
      float e0 = __expf(dd[mt][0] - diag - st) + KEPS;
      float e1 = __expf(dd[mt][1] - diag - st) + KEPS;
      float e2 = __expf(dd[mt][2] - diag - st) + KEPS;
      float e3 = __expf(dd[mt][3] - diag - st) + KEPS;
      dacc += e0 * kc.x + e1 * kc.y + e2 * kc.z + e3 * kc.w;
      f16x4 ph;
      ph[0] = (f16)e0; ph[1] = (f16)e1; ph[2] = (f16)e2; ph[3] = (f16)e3;
      *(f16x4*)(&pht[w][l15 * 264 + mt * 16 + q4 * 4]) = ph;
    }
    dacc += __shfl_xor(dacc, 16, 64);
    dacc += __shfl_xor(dacc, 32, 64);
    float dinv = 1.0f / dacc;
    f32x4 ao[4];
#pragma unroll
    for (int r = 0; r < 4; ++r) ao[r] = (f32x4){0.f, 0.f, 0.f, 0.f};
#pragma unroll
    for (int ks2 = 0; ks2 < 8; ++ks2) {
      f16x8 bph = *(const f16x8*)(&pht[w][l15 * 264 + ks2 * 32 + q4 * 8]);
#pragma unroll
      for (int rte = 0; rte < 4; ++rte) {
        f16x8 act = *(const f16x8*)(ctb + (size_t)(l15 + 16 * rte) * 256 + ks2 * 32 + q4 * 8);
        ao[rte] = MFMA16(act, bph, ao[rte]);  // outT: row e, col n
      }
    }
#pragma unroll
    for (int rte = 0; rte < 4; ++rte) {
      float4 o;
      o.x = ao[rte][0] * dinv;
      o.y = ao[rte][1] * dinv;
      o.z = ao[rte][2] * dinv;
      o.w = ao[rte][3] * dinv;
      *(float4*)(obh + (size_t)(n0 + l15) * 64 + rte * 16 + q4 * 4) = o;
    }
  }
}

extern "C" void kernel_launch(void* const* d_in, const int* in_sizes, int n_in,
                              void* d_out, int out_size, void* d_ws, size_t ws_size,
                              hipStream_t stream) {
  const float* q = (const float*)d_in[0];
  const float* k = (const float*)d_in[1];
  const float* v = (const float*)d_in[2];
  const float* proj = (const float*)d_in[3];
  float* out = (float*)d_out;
  float* ws = (float*)d_ws;
  // ws layout (floats): stab[64][8] | kcum[64][256] | ctxT f16[64][64][256]  (~2.07 MB)
  float* ws_stab = ws;                    // 512 floats (1024 reserved)
  float* ws_kcum = ws + 1024;             // 16384 floats
  f16*   ws_ctxT = (f16*)(ws + 17408);    // 1,048,576 f16
  // d_out scratch (67 MB): ctx partials 33.5 MB + kcum partials 0.5 MB; all plain
  // stores (no atomics -> no 582 MB write-through), fully consumed by K2b before
  // K3 overwrites every element of d_out. No memsets needed: every scratch byte is
  // written before it is read.
  float* ctx_part  = out;                 // [64][8][256][64] floats
  float* kcum_part = out + 8388608;       // [64][8][256] floats
  k1_stab<<<512, 256, 0, stream>>>(k, proj, ws_stab);
  k2_ctx<<<512, 256, 0, stream>>>(k, v, proj, ws_stab, ctx_part, kcum_part);
  k2b_t<<<256, 256, 0, stream>>>(ctx_part, kcum_part, ws_kcum, ws_ctxT);
  k3_out<<<1024, 256, 0, stream>>>(q, proj, ws_kcum, ws_ctxT, out);
}